// Round 1
// baseline (1158.899 us; speedup 1.0000x reference)
//
#include <hip/hip_runtime.h>

// MemorizingLlamaDecoderLayer — B=2 S=1024 D=2048 H=16 HD=128 F=8192 M=8192
// Round 0: correctness-first bf16-MFMA pipeline with fp64 argmax rescue.

typedef unsigned short u16;
typedef __bf16 bf16x8 __attribute__((ext_vector_type(8)));
typedef float f32x4 __attribute__((ext_vector_type(4)));

__device__ __forceinline__ float bf2f(u16 h) {
  unsigned u = ((unsigned)h) << 16; float f; __builtin_memcpy(&f, &u, 4); return f;
}
__device__ __forceinline__ u16 f2bf(float f) {
  unsigned u; __builtin_memcpy(&u, &f, 4);
  u += 0x7fff + ((u >> 16) & 1);           // RNE
  return (u16)(u >> 16);
}
__device__ __forceinline__ void gload_lds16(const u16* g, u16* l) {
  __builtin_amdgcn_global_load_lds((__attribute__((address_space(1))) void*)(u16*)g,
                                   (__attribute__((address_space(3))) void*)l, 16, 0, 0);
}

// ---------------- elementwise / prep kernels ----------------

__global__ void cast_f32_bf16(const float* __restrict__ in, u16* __restrict__ out, long n) {
  long i = ((long)blockIdx.x * 256 + threadIdx.x) * 8;
  if (i >= n) return;
  float4 a = *(const float4*)(in + i);
  float4 b = *(const float4*)(in + i + 4);
  uint4 o;
  o.x = f2bf(a.x) | ((unsigned)f2bf(a.y) << 16);
  o.y = f2bf(a.z) | ((unsigned)f2bf(a.w) << 16);
  o.z = f2bf(b.x) | ((unsigned)f2bf(b.y) << 16);
  o.w = f2bf(b.z) | ((unsigned)f2bf(b.w) << 16);
  *(uint4*)(out + i) = o;
}

// in [R][C] f32  ->  out [C][R] bf16
__global__ void transpose_cast(const float* __restrict__ in, u16* __restrict__ out, int R, int C) {
  __shared__ float t[32][33];
  int tid = threadIdx.x;
  int tr = tid >> 3;            // 0..31
  int tc = (tid & 7) * 4;       // 0,4,..,28
  long bx = blockIdx.x, by = blockIdx.y;
  float4 v = *(const float4*)(in + (by * 32 + tr) * (long)C + bx * 32 + tc);
  t[tr][tc] = v.x; t[tr][tc + 1] = v.y; t[tr][tc + 2] = v.z; t[tr][tc + 3] = v.w;
  __syncthreads();
  unsigned lo = f2bf(t[tc][tr])     | ((unsigned)f2bf(t[tc + 1][tr]) << 16);
  unsigned hi = f2bf(t[tc + 2][tr]) | ((unsigned)f2bf(t[tc + 3][tr]) << 16);
  uint2 o; o.x = lo; o.y = hi;
  *(uint2*)(out + (bx * 32 + tr) * (long)R + by * 32 + tc) = o;
}

__global__ void rope_table(const int* __restrict__ pos, float* __restrict__ cs) {
  int t = blockIdx.x * 256 + threadIdx.x;   // 2048*64
  int d = t & 63, rs = t >> 6;
  double freq = exp(((double)(-2 * d) / 128.0) * log(10000.0));
  double ang = (double)pos[rs] * freq;
  cs[rs * 128 + d]      = (float)cos(ang);
  cs[rs * 128 + 64 + d] = (float)sin(ang);
}

__global__ void rope_apply(u16* __restrict__ q, u16* __restrict__ k, const float* __restrict__ cs) {
  int t = blockIdx.x * 256 + threadIdx.x;   // 2048*16*64
  int d = t & 63, h = (t >> 6) & 15, rs = t >> 10;
  float c = cs[rs * 128 + d], s = cs[rs * 128 + 64 + d];
  long i1 = (long)rs * 2048 + h * 128 + d, i2 = i1 + 64;
  float q1 = bf2f(q[i1]), q2 = bf2f(q[i2]);
  q[i1] = f2bf(q1 * c - q2 * s); q[i2] = f2bf(q2 * c + q1 * s);
  float k1 = bf2f(k[i1]), k2 = bf2f(k[i2]);
  k[i1] = f2bf(k1 * c - k2 * s); k[i2] = f2bf(k2 * c + k1 * s);
}

__global__ void silu_mul(const u16* __restrict__ g, const u16* __restrict__ u,
                         u16* __restrict__ h, long n) {
  long i = ((long)blockIdx.x * 256 + threadIdx.x) * 8;
  if (i >= n) return;
  uint4 gv = *(const uint4*)(g + i);
  uint4 uv = *(const uint4*)(u + i);
  unsigned gw[4] = {gv.x, gv.y, gv.z, gv.w};
  unsigned uw[4] = {uv.x, uv.y, uv.z, uv.w};
  unsigned ow[4];
  #pragma unroll
  for (int j = 0; j < 4; ++j) {
    float g0 = bf2f((u16)(gw[j] & 0xffff)), g1 = bf2f((u16)(gw[j] >> 16));
    float u0 = bf2f((u16)(uw[j] & 0xffff)), u1 = bf2f((u16)(uw[j] >> 16));
    float s0 = g0 / (1.f + __expf(-g0)) * u0;
    float s1 = g1 / (1.f + __expf(-g1)) * u1;
    ow[j] = f2bf(s0) | ((unsigned)f2bf(s1) << 16);
  }
  uint4 o; o.x = ow[0]; o.y = ow[1]; o.z = ow[2]; o.w = ow[3];
  *(uint4*)(h + i) = o;
}

// ---------------- argmax rescue (fp64 exact) ----------------

__global__ void argmax_rescue(const float* __restrict__ scores, const float* __restrict__ hid,
                              const float* __restrict__ memb, int* __restrict__ nn) {
  int row = blockIdx.x, tid = threadIdx.x;
  const float* srow = scores + (long)row * 8192;
  __shared__ float sred[4];
  __shared__ double dred[4];
  __shared__ int cnt;
  __shared__ int cands[64];
  float mx = -1e30f;
  for (int c = tid; c < 8192; c += 256) mx = fmaxf(mx, srow[c]);
  #pragma unroll
  for (int m = 32; m; m >>= 1) mx = fmaxf(mx, __shfl_xor(mx, m, 64));
  if ((tid & 63) == 0) sred[tid >> 6] = mx;
  if (tid == 0) cnt = 0;
  __syncthreads();
  mx = fmaxf(fmaxf(sred[0], sred[1]), fmaxf(sred[2], sred[3]));
  for (int c = tid; c < 8192; c += 256)
    if (srow[c] > mx - 3.0f) { int p = atomicAdd(&cnt, 1); if (p < 64) cands[p] = c; }
  __syncthreads();
  int ncand = cnt < 64 ? cnt : 64;
  const float* h = hid + (long)row * 2048;
  double best = -1e300; int bestIdx = 0x7fffffff;
  for (int ci = 0; ci < ncand; ++ci) {
    int idx = cands[ci];
    const float* mrow = memb + (long)idx * 2048;
    double s = 0;
    for (int d = tid; d < 2048; d += 256) s += (double)h[d] * (double)mrow[d];
    #pragma unroll
    for (int m = 32; m; m >>= 1) s += __shfl_xor(s, m, 64);
    if ((tid & 63) == 0) dred[tid >> 6] = s;
    __syncthreads();
    s = dred[0] + dred[1] + dred[2] + dred[3];
    __syncthreads();
    if (s > best || (s == best && idx < bestIdx)) { best = s; bestIdx = idx; }
  }
  if (tid == 0) nn[row] = bestIdx;
}

// ---------------- merged mix + RMS1 ----------------

__global__ void merged_rms1(const float* __restrict__ hid, const float* __restrict__ memb,
                            const int* __restrict__ nn, const float* __restrict__ gate,
                            const float* __restrict__ w1, float* __restrict__ merged,
                            u16* __restrict__ xbf) {
  int row = blockIdx.x, tid = threadIdx.x;
  const float* h = hid + (long)row * 2048;
  const float* m = memb + (long)nn[row] * 2048;
  int d0 = tid * 8;
  float4 h0 = *(const float4*)(h + d0), h1 = *(const float4*)(h + d0 + 4);
  float4 m0 = *(const float4*)(m + d0), m1 = *(const float4*)(m + d0 + 4);
  float hv[8] = {h0.x, h0.y, h0.z, h0.w, h1.x, h1.y, h1.z, h1.w};
  float mv[8] = {m0.x, m0.y, m0.z, m0.w, m1.x, m1.y, m1.z, m1.w};
  float sh = 0, sm = 0;
  #pragma unroll
  for (int j = 0; j < 8; ++j) { sh += hv[j] * hv[j]; sm += mv[j] * mv[j]; }
  __shared__ float sa[4], sb[4];
  #pragma unroll
  for (int mm = 32; mm; mm >>= 1) { sh += __shfl_xor(sh, mm, 64); sm += __shfl_xor(sm, mm, 64); }
  if ((tid & 63) == 0) { sa[tid >> 6] = sh; sb[tid >> 6] = sm; }
  __syncthreads();
  sh = sa[0] + sa[1] + sa[2] + sa[3];
  sm = sb[0] + sb[1] + sb[2] + sb[3];
  __syncthreads();
  float nh = sqrtf(sh) + 1e-4f, nmv = sqrtf(sm) + 1e-4f;
  float ratio = nh / nmv;
  float4 g0 = *(const float4*)(gate + d0), g1 = *(const float4*)(gate + d0 + 4);
  float gv[8] = {g0.x, g0.y, g0.z, g0.w, g1.x, g1.y, g1.z, g1.w};
  float mg[8]; float s2 = 0;
  #pragma unroll
  for (int j = 0; j < 8; ++j) {
    float g = 1.f / (1.f + __expf(-gv[j]));
    float v = g * hv[j] + (1.f - g) * mv[j] * ratio;
    mg[j] = v; s2 += v * v;
  }
  #pragma unroll
  for (int mm = 32; mm; mm >>= 1) s2 += __shfl_xor(s2, mm, 64);
  if ((tid & 63) == 0) sa[tid >> 6] = s2;
  __syncthreads();
  s2 = sa[0] + sa[1] + sa[2] + sa[3];
  float sc = 1.0f / sqrtf(s2 * (1.0f / 2048.0f) + 1e-6f);
  float4 o0; o0.x = mg[0]; o0.y = mg[1]; o0.z = mg[2]; o0.w = mg[3];
  float4 o1; o1.x = mg[4]; o1.y = mg[5]; o1.z = mg[6]; o1.w = mg[7];
  *(float4*)(merged + (long)row * 2048 + d0) = o0;
  *(float4*)(merged + (long)row * 2048 + d0 + 4) = o1;
  float4 w0 = *(const float4*)(w1 + d0), w1v = *(const float4*)(w1 + d0 + 4);
  float wv[8] = {w0.x, w0.y, w0.z, w0.w, w1v.x, w1v.y, w1v.z, w1v.w};
  uint4 ob;
  ob.x = f2bf(mg[0] * sc * wv[0]) | ((unsigned)f2bf(mg[1] * sc * wv[1]) << 16);
  ob.y = f2bf(mg[2] * sc * wv[2]) | ((unsigned)f2bf(mg[3] * sc * wv[3]) << 16);
  ob.z = f2bf(mg[4] * sc * wv[4]) | ((unsigned)f2bf(mg[5] * sc * wv[5]) << 16);
  ob.w = f2bf(mg[6] * sc * wv[6]) | ((unsigned)f2bf(mg[7] * sc * wv[7]) << 16);
  *(uint4*)(xbf + (long)row * 2048 + d0) = ob;
}

__global__ void rms2_kernel(const float* __restrict__ in, const float* __restrict__ w,
                            u16* __restrict__ outb) {
  int row = blockIdx.x, tid = threadIdx.x;
  const float* x = in + (long)row * 2048;
  int d0 = tid * 8;
  float4 a = *(const float4*)(x + d0), b = *(const float4*)(x + d0 + 4);
  float v[8] = {a.x, a.y, a.z, a.w, b.x, b.y, b.z, b.w};
  float s = 0;
  #pragma unroll
  for (int j = 0; j < 8; ++j) s += v[j] * v[j];
  __shared__ float sred[4];
  #pragma unroll
  for (int m = 32; m; m >>= 1) s += __shfl_xor(s, m, 64);
  if ((tid & 63) == 0) sred[tid >> 6] = s;
  __syncthreads();
  s = sred[0] + sred[1] + sred[2] + sred[3];
  float sc = 1.0f / sqrtf(s * (1.0f / 2048.0f) + 1e-6f);
  float4 w0 = *(const float4*)(w + d0), w1v = *(const float4*)(w + d0 + 4);
  float wv[8] = {w0.x, w0.y, w0.z, w0.w, w1v.x, w1v.y, w1v.z, w1v.w};
  uint4 o;
  o.x = f2bf(v[0] * sc * wv[0]) | ((unsigned)f2bf(v[1] * sc * wv[1]) << 16);
  o.y = f2bf(v[2] * sc * wv[2]) | ((unsigned)f2bf(v[3] * sc * wv[3]) << 16);
  o.z = f2bf(v[4] * sc * wv[4]) | ((unsigned)f2bf(v[5] * sc * wv[5]) << 16);
  o.w = f2bf(v[6] * sc * wv[6]) | ((unsigned)f2bf(v[7] * sc * wv[7]) << 16);
  *(uint4*)(outb + (long)row * 2048 + d0) = o;
}

// ---------------- causal softmax (in-place P as bf16) ----------------

__global__ void softmax_causal(float* __restrict__ attnS) {
  int rowg = blockIdx.x;                  // 32*1024
  int z = rowg >> 10, r = rowg & 1023;
  float* srow = attnS + (long)z * 1048576 + (long)r * 1024;
  u16* prow = (u16*)attnS + (long)z * 2097152 + (long)r * 2048;
  int tid = threadIdx.x;
  __shared__ float sred[4];
  float v[4]; float mx = -1e30f;
  #pragma unroll
  for (int u = 0; u < 4; ++u) {
    int c = tid + u * 256;
    v[u] = (c <= r) ? srow[c] : -1e30f;
    mx = fmaxf(mx, v[u]);
  }
  #pragma unroll
  for (int m = 32; m; m >>= 1) mx = fmaxf(mx, __shfl_xor(mx, m, 64));
  if ((tid & 63) == 0) sred[tid >> 6] = mx;
  __syncthreads();
  mx = fmaxf(fmaxf(sred[0], sred[1]), fmaxf(sred[2], sred[3]));
  __syncthreads();
  float s = 0;
  #pragma unroll
  for (int u = 0; u < 4; ++u) {
    int c = tid + u * 256;
    v[u] = (c <= r) ? __expf(v[u] - mx) : 0.f;
    s += v[u];
  }
  #pragma unroll
  for (int m = 32; m; m >>= 1) s += __shfl_xor(s, m, 64);
  if ((tid & 63) == 0) sred[tid >> 6] = s;
  __syncthreads();
  s = sred[0] + sred[1] + sred[2] + sred[3];
  float inv = 1.0f / s;
  __syncthreads();
  #pragma unroll
  for (int u = 0; u < 4; ++u) prow[tid + u * 256] = f2bf(v[u] * inv);
}

// ---------------- bf16 NT GEMM (m97 structure): C = A (RxK) * B^T (NxK) ----------------
// EPI: 0=f32 store, 1=f32 scale+causal, 2=bf16 store, 3=bf16 transposed (V->V^T), 4=f32+residual
template<int EPI>
__global__ void gemm_nt(const u16* __restrict__ A, long aStrB, long aStrH, int lda,
                        const u16* __restrict__ B, long bStrB, long bStrH, int ldb,
                        void* __restrict__ C, long cStrB, long cStrH, int ldc,
                        const float* __restrict__ Res, int ldres,
                        int K, float scale) {
  if (EPI == 1 && blockIdx.x > blockIdx.y) return;   // causal: skip fully-masked tiles
  __shared__ u16 As[4096], Bs[4096];                 // 128x32 each
  const int z = blockIdx.z, zb = z >> 4, zh = z & 15;
  const u16* Ab = A + zb * aStrB + zh * aStrH;
  const u16* Bb = B + zb * bStrB + zh * bStrH;
  const int tid = threadIdx.x, lane = tid & 63;
  const int wv = tid >> 6, wr = wv >> 1, wc = wv & 1;
  const long rowBase = (long)blockIdx.y * 128, colBase = (long)blockIdx.x * 128;
  f32x4 acc[4][4] = {};
  const int e0 = tid * 8, e1 = e0 + 2048;
  const int r0 = e0 >> 5, c0 = e0 & 31;
  const int r1 = e1 >> 5, c1 = e1 & 31;
  const u16* aP0 = Ab + (rowBase + r0) * (long)lda + c0;
  const u16* aP1 = Ab + (rowBase + r1) * (long)lda + c1;
  const u16* bP0 = Bb + (colBase + r0) * (long)ldb + c0;
  const u16* bP1 = Bb + (colBase + r1) * (long)ldb + c1;
  const int kk = (lane >> 4) * 8, r16 = lane & 15;
  const u16* aL[4]; const u16* bL[4];
  #pragma unroll
  for (int i = 0; i < 4; ++i) {
    aL[i] = As + (wr * 64 + i * 16 + r16) * 32 + kk;
    bL[i] = Bs + (wc * 64 + i * 16 + r16) * 32 + kk;
  }
  for (int kt = 0; kt < K; kt += 32) {
    __syncthreads();
    gload_lds16(aP0 + kt, As + e0);
    gload_lds16(aP1 + kt, As + e1);
    gload_lds16(bP0 + kt, Bs + e0);
    gload_lds16(bP1 + kt, Bs + e1);
    __syncthreads();
    bf16x8 af[4], bfr[4];
    #pragma unroll
    for (int i = 0; i < 4; ++i) af[i] = *(const bf16x8*)aL[i];
    #pragma unroll
    for (int j = 0; j < 4; ++j) bfr[j] = *(const bf16x8*)bL[j];
    #pragma unroll
    for (int i = 0; i < 4; ++i)
      #pragma unroll
      for (int j = 0; j < 4; ++j)
        acc[i][j] = __builtin_amdgcn_mfma_f32_16x16x32_bf16(af[i], bfr[j], acc[i][j], 0, 0, 0);
  }
  const int rg = (lane >> 4) * 4;
  float* Cf = (float*)C + zb * cStrB + zh * cStrH;
  u16* Cb = (u16*)C + zb * cStrB + zh * cStrH;
  #pragma unroll
  for (int i = 0; i < 4; ++i) {
    #pragma unroll
    for (int j = 0; j < 4; ++j) {
      #pragma unroll
      for (int q = 0; q < 4; ++q) {
        long row = rowBase + wr * 64 + i * 16 + rg + q;
        long col = colBase + wc * 64 + j * 16 + r16;
        float v = acc[i][j][q];
        if (EPI == 0) Cf[row * ldc + col] = v;
        else if (EPI == 1) { v *= scale; if (col > row) v = -1e30f; Cf[row * ldc + col] = v; }
        else if (EPI == 2) Cb[row * ldc + col] = f2bf(v);
        else if (EPI == 3) Cb[(row >> 10) * 2097152L + col * 1024 + (row & 1023)] = f2bf(v);
        else if (EPI == 4) Cf[row * ldc + col] = v + Res[row * ldres + col];
      }
    }
  }
}

// ---------------- host ----------------

extern "C" void kernel_launch(void* const* d_in, const int* in_sizes, int n_in,
                              void* d_out, int out_size, void* d_ws, size_t ws_size,
                              hipStream_t stream) {
  (void)in_sizes; (void)n_in; (void)out_size; (void)ws_size;
  const float* hid  = (const float*)d_in[0];
  const int*   pos  = (const int*)d_in[1];
  const float* memb = (const float*)d_in[2];
  const float* gate = (const float*)d_in[3];
  const float* wq   = (const float*)d_in[4];
  const float* wk   = (const float*)d_in[5];
  const float* wvp  = (const float*)d_in[6];
  const float* wo   = (const float*)d_in[7];
  const float* wg   = (const float*)d_in[8];
  const float* wu   = (const float*)d_in[9];
  const float* wd   = (const float*)d_in[10];
  const float* w1   = (const float*)d_in[11];
  const float* w2   = (const float*)d_in[12];
  float* out = (float*)d_out;
  char* ws = (char*)d_ws;

  // Arena (bytes). Union region U=[0,134217728): phase2 {hid_bf,mem_bf,scores},
  // phase5 {attnS/P}, phase8 {g1,u1,h}. Total footprint ~337 MB.
  u16*   hid_bf  = (u16*)(ws + 0);
  u16*   mem_bf  = (u16*)(ws + 8388608);
  float* scores  = (float*)(ws + 41943040);
  float* attnS   = (float*)(ws + 0);
  u16*   P_bf    = (u16*)(ws + 0);
  u16*   g1_bf   = (u16*)(ws + 0);
  u16*   u1_bf   = (u16*)(ws + 33554432);
  u16*   h_bf    = (u16*)(ws + 67108864);
  u16*   wqT     = (u16*)(ws + 134217728);
  u16*   wkT     = (u16*)(ws + 142606336);
  u16*   wvT     = (u16*)(ws + 150994944);
  u16*   woT     = (u16*)(ws + 159383552);
  u16*   wgT     = (u16*)(ws + 167772160);
  u16*   wuT     = (u16*)(ws + 201326592);
  u16*   wdT     = (u16*)(ws + 234881024);
  int*   nn      = (int*)(ws + 268435456);
  float* ropecs  = (float*)(ws + 268443648);
  float* mergedp = (float*)(ws + 269492224);
  u16*   x_bf    = (u16*)(ws + 286269440);
  u16*   q_bf    = (u16*)(ws + 294658048);
  u16*   k_bf    = (u16*)(ws + 303046656);
  u16*   vt      = (u16*)(ws + 311435264);
  u16*   ctx_bf  = (u16*)(ws + 319823872);
  float* o_f     = (float*)(ws + 328212480);
  u16*   y_bf    = (u16*)(ws + 344989696);

  // 1. casts & weight transposes (bf16, NT layout for all GEMMs)
  cast_f32_bf16<<<2048, 256, 0, stream>>>(hid, hid_bf, 4194304L);
  cast_f32_bf16<<<8192, 256, 0, stream>>>(memb, mem_bf, 16777216L);
  transpose_cast<<<dim3(64, 64), 256, 0, stream>>>(wq, wqT, 2048, 2048);
  transpose_cast<<<dim3(64, 64), 256, 0, stream>>>(wk, wkT, 2048, 2048);
  transpose_cast<<<dim3(64, 64), 256, 0, stream>>>(wvp, wvT, 2048, 2048);
  transpose_cast<<<dim3(64, 64), 256, 0, stream>>>(wo, woT, 2048, 2048);
  transpose_cast<<<dim3(256, 64), 256, 0, stream>>>(wg, wgT, 2048, 8192);
  transpose_cast<<<dim3(256, 64), 256, 0, stream>>>(wu, wuT, 2048, 8192);
  transpose_cast<<<dim3(64, 256), 256, 0, stream>>>(wd, wdT, 8192, 2048);
  rope_table<<<512, 256, 0, stream>>>(pos, ropecs);

  // 2. kNN: bf16 scores GEMM + fp64 rescue argmax + merged/RMS1
  gemm_nt<0><<<dim3(64, 16, 1), 256, 0, stream>>>(hid_bf, 0, 0, 2048, mem_bf, 0, 0, 2048,
                                                  scores, 0, 0, 8192, nullptr, 0, 2048, 1.0f);
  argmax_rescue<<<2048, 256, 0, stream>>>(scores, hid, memb, nn);
  merged_rms1<<<2048, 256, 0, stream>>>(hid, memb, nn, gate, w1, mergedp, x_bf);

  // 3. QKV + RoPE  (V stored transposed for the PV NT-GEMM)
  gemm_nt<2><<<dim3(16, 16, 1), 256, 0, stream>>>(x_bf, 0, 0, 2048, wqT, 0, 0, 2048,
                                                  q_bf, 0, 0, 2048, nullptr, 0, 2048, 1.0f);
  gemm_nt<2><<<dim3(16, 16, 1), 256, 0, stream>>>(x_bf, 0, 0, 2048, wkT, 0, 0, 2048,
                                                  k_bf, 0, 0, 2048, nullptr, 0, 2048, 1.0f);
  gemm_nt<3><<<dim3(16, 16, 1), 256, 0, stream>>>(x_bf, 0, 0, 2048, wvT, 0, 0, 2048,
                                                  vt, 0, 0, 2048, nullptr, 0, 2048, 1.0f);
  rope_apply<<<8192, 256, 0, stream>>>(q_bf, k_bf, ropecs);

  // 4. attention: QK^T (causal, scaled) -> softmax (P bf16 in-place) -> PV -> +residual via WO
  gemm_nt<1><<<dim3(8, 8, 32), 256, 0, stream>>>(q_bf, 2097152, 128, 2048,
                                                 k_bf, 2097152, 128, 2048,
                                                 attnS, 16777216, 1048576, 1024,
                                                 nullptr, 0, 128, 0.08838834764831845f);
  softmax_causal<<<32768, 256, 0, stream>>>(attnS);
  gemm_nt<2><<<dim3(1, 8, 32), 256, 0, stream>>>(P_bf, 33554432, 2097152, 2048,
                                                 vt, 2097152, 131072, 1024,
                                                 ctx_bf, 2097152, 128, 2048,
                                                 nullptr, 0, 1024, 1.0f);
  gemm_nt<4><<<dim3(16, 16, 1), 256, 0, stream>>>(ctx_bf, 0, 0, 2048, woT, 0, 0, 2048,
                                                  o_f, 0, 0, 2048, mergedp, 2048, 2048, 1.0f);

  // 5. MLP
  rms2_kernel<<<2048, 256, 0, stream>>>(o_f, w2, y_bf);
  gemm_nt<2><<<dim3(64, 16, 1), 256, 0, stream>>>(y_bf, 0, 0, 2048, wgT, 0, 0, 2048,
                                                  g1_bf, 0, 0, 8192, nullptr, 0, 2048, 1.0f);
  gemm_nt<2><<<dim3(64, 16, 1), 256, 0, stream>>>(y_bf, 0, 0, 2048, wuT, 0, 0, 2048,
                                                  u1_bf, 0, 0, 8192, nullptr, 0, 2048, 1.0f);
  silu_mul<<<8192, 256, 0, stream>>>(g1_bf, u1_bf, h_bf, 16777216L);
  gemm_nt<4><<<dim3(16, 16, 1), 256, 0, stream>>>(h_bf, 0, 0, 8192, wdT, 0, 0, 8192,
                                                  out, 0, 0, 2048, o_f, 2048, 8192, 1.0f);
}